// Round 5
// baseline (165.339 us; speedup 1.0000x reference)
//
#include <hip/hip_runtime.h>
#include <math.h>

typedef _Float16 half8 __attribute__((ext_vector_type(8)));
typedef _Float16 half4 __attribute__((ext_vector_type(4)));
typedef float f32x4 __attribute__((ext_vector_type(4)));

constexpr int N = 2000;
constexpr int NP = 2048;   // padded row count for f16 tensors
constexpr int H = 8;
constexpr int D = 32;
constexpr float SCL = 25.0f;
constexpr float FM = 25.0f;  // fixed softmax max (scores bounded by 25)

#define MFMA16(a,b,c)  __builtin_amdgcn_mfma_f32_16x16x32_f16((a),(b),(c),0,0,0)
#define MFMA16K(a,b,c) __builtin_amdgcn_mfma_f32_16x16x16f16((a),(b),(c),0,0,0)

// ---- ws layout (byte offsets) ----
// STi  f32 [2z][8h][2048]        @ 0          (131072 B)   stores 1/S
// SIM  f32 [2000][2000]          @ 131072     (16000000 B)
// XPH  f16 [8mc][8h][2000][32]   @ 16131072   (8192000 B)
// F16  Qch,Kch,Qrh,Krh,Vnh [8][2048][32]; Vth [8][32][2048] @ 24323072 (6x1048576 B)
// Wch  f16 [768][256]            @ 30614528   (393216 B)
// Wrh  f16 [768][256]            @ 31007744   (393216 B)
// Mask u8  [2000][2000]          @ 31400960   (4000000 B)   total ~35.4 MB

// ================= K0: convert W to f16 =================
__global__ __launch_bounds__(256) void wconv_kernel(
    const float* __restrict__ Wc, const float* __restrict__ Wr,
    _Float16* __restrict__ Wch, _Float16* __restrict__ Wrh)
{
    const int i = blockIdx.x * 256 + threadIdx.x;  // grid 768 -> 196608 exactly
    Wch[i] = (_Float16)Wc[i];
    Wrh[i] = (_Float16)Wr[i];
}

// ================= K1: QKV projection via MFMA + L2 norm =================
__global__ __launch_bounds__(256) void qkv_kernel(
    const float* __restrict__ xc, const float* __restrict__ xr,
    const _Float16* __restrict__ Wch, const _Float16* __restrict__ Wrh,
    _Float16* __restrict__ Qch, _Float16* __restrict__ Kch,
    _Float16* __restrict__ Qrh, _Float16* __restrict__ Krh,
    _Float16* __restrict__ Vnh, _Float16* __restrict__ Vth,
    float* __restrict__ out)
{
    constexpr int XS = 264;  // xs row stride (halfs), +8 pad
    __shared__ _Float16 xs[16 * XS];
    const int t = threadIdx.x;
    const int n0 = blockIdx.x * 16;
    const int by = blockIdx.y;             // 0..4: (cls q,k,v), (reg q,k)
    const int which = (by < 3) ? by : (by - 3);
    const bool isCls = by < 3;
    const float* x = isCls ? xc : xr;
    const _Float16* Wh = isCls ? Wch : Wrh;

    #pragma unroll
    for (int it = 0; it < 4; ++it) {
        const int f = t + it * 256;        // float4 index over 16x64
        const int row = f >> 6, c4 = f & 63;
        const float4 v = *(const float4*)(x + (size_t)(n0 + row) * 256 + c4 * 4);
        half4 hv; hv[0]=(_Float16)v.x; hv[1]=(_Float16)v.y; hv[2]=(_Float16)v.z; hv[3]=(_Float16)v.w;
        *(half4*)&xs[row * XS + c4 * 4] = hv;
    }
    __syncthreads();

    const int w = t >> 6, l = t & 63;
    const int lr = l & 15, lg = l >> 4;
    const int obase = which * 256 + w * 64;
    f32x4 acc[4] = {{0,0,0,0},{0,0,0,0},{0,0,0,0},{0,0,0,0}};
    for (int k0 = 0; k0 < 256; k0 += 32) {
        const half8 aX = *(const half8*)&xs[lr * XS + k0 + lg * 8];
        #pragma unroll
        for (int s = 0; s < 4; ++s) {
            const half8 bW = *(const half8*)(Wh + (size_t)(obase + s * 16 + lr) * 256 + k0 + lg * 8);
            acc[s] = MFMA16(aX, bW, acc[s]);
        }
    }
    #pragma unroll
    for (int p = 0; p < 2; ++p) {
        const int h = 2 * w + p;
        float ss[4];
        #pragma unroll
        for (int j = 0; j < 4; ++j) {
            float v = acc[2*p][j]*acc[2*p][j] + acc[2*p+1][j]*acc[2*p+1][j];
            #pragma unroll
            for (int off = 1; off < 16; off <<= 1) v += __shfl_xor(v, off);
            ss[j] = sqrtf(v) + 1e-8f;
        }
        if (which < 2) {
            _Float16* Qd = isCls ? (which == 0 ? Qch : Kch) : (which == 0 ? Qrh : Krh);
            #pragma unroll
            for (int sh = 0; sh < 2; ++sh)
                #pragma unroll
                for (int j = 0; j < 4; ++j)
                    Qd[((size_t)h*NP + n0 + lg*4 + j)*D + sh*16 + lr] = (_Float16)(acc[2*p+sh][j] / ss[j]);
        } else {
            #pragma unroll
            for (int sh = 0; sh < 2; ++sh) {
                const int d = sh * 16 + lr;
                half4 tv;
                #pragma unroll
                for (int j = 0; j < 4; ++j) {
                    const float raw = acc[2*p+sh][j];
                    Vnh[((size_t)h*NP + n0 + lg*4 + j)*D + d] = (_Float16)(raw / ss[j]);
                    out[(size_t)(n0 + lg*4 + j)*512 + 256 + h*D + d] = raw;
                    tv[j] = (_Float16)raw;
                }
                *(half4*)(Vth + ((size_t)h*D + d)*NP + n0 + lg*4) = tv;
            }
        }
    }
}

// ================= K2: softmax denom (fixed max M=25) via MFMA, stores 1/S =================
__global__ __launch_bounds__(512) void stats_kernel(
    const _Float16* __restrict__ Qch, const _Float16* __restrict__ Kch,
    const _Float16* __restrict__ Qrh, const _Float16* __restrict__ Krh,
    const float* __restrict__ clsScore, const float* __restrict__ fgScore,
    float* __restrict__ STi)
{
    __shared__ float Ssh[4][2][16];
    const int t = threadIdx.x;
    const int w = t >> 6, l = t & 63;
    const int nsub = w >> 1, mhalf = w & 1;
    const int n0 = blockIdx.x * 64 + nsub * 16;
    const int h = blockIdx.y, z = blockIdx.z;
    const _Float16* Q = z ? Qrh : Qch;
    const _Float16* K = z ? Krh : Kch;
    const float* score = z ? fgScore : clsScore;
    const int lr = l & 15, lg = l >> 4;
    const half8 aQ = *(const half8*)(Q + ((size_t)h*NP + n0 + lr)*D + lg*8);
    float S[4] = {0.f, 0.f, 0.f, 0.f};
    const int msBeg = mhalf ? 63 : 0;
    const int msEnd = mhalf ? 125 : 63;
    for (int ms = msBeg; ms < msEnd; ++ms) {
        const int m = ms * 16 + lr;
        const half8 bK = *(const half8*)(K + ((size_t)h*NP + m)*D + lg*8);
        f32x4 z4 = {0.f, 0.f, 0.f, 0.f};
        const f32x4 c = MFMA16(aQ, bK, z4);
        const float sm = SCL * score[m];
        #pragma unroll
        for (int j = 0; j < 4; ++j) S[j] += __expf(fmaf(c[j], sm, -FM));
    }
    #pragma unroll
    for (int j = 0; j < 4; ++j) {
        #pragma unroll
        for (int off = 1; off < 16; off <<= 1) S[j] += __shfl_xor(S[j], off);
    }
    if (lr == 0) {
        #pragma unroll
        for (int j = 0; j < 4; ++j) Ssh[nsub][mhalf][lg*4 + j] = S[j];
    }
    __syncthreads();
    if (t < 64) {
        const int ns = t >> 4, rl = t & 15;
        STi[((size_t)z*H + h)*NP + blockIdx.x*64 + ns*16 + rl]
            = 1.f / (Ssh[ns][0][rl] + Ssh[ns][1][rl]);
    }
}

// ================= K3: mean-over-h of Vn.Vn^T -> u8 mask (MFMA) =================
__global__ __launch_bounds__(256) void vvmask_kernel(
    const _Float16* __restrict__ Vnh, unsigned char* __restrict__ Mask)
{
    const int t = threadIdx.x;
    const int w = t >> 6, l = t & 63;
    const int n0 = blockIdx.y * 16;
    const int m00 = blockIdx.x * 256 + w * 64;
    const int lr = l & 15, lg = l >> 4;
    half8 aV[8];
    #pragma unroll
    for (int h = 0; h < 8; ++h)
        aV[h] = *(const half8*)(Vnh + ((size_t)(h*NP + n0 + lr))*D + lg*8);
    for (int s = 0; s < 4; ++s) {
        const int mb = m00 + s*16;
        f32x4 acc = {0.f, 0.f, 0.f, 0.f};
        #pragma unroll
        for (int h = 0; h < 8; ++h) {
            const half8 bV = *(const half8*)(Vnh + ((size_t)(h*NP + mb + lr))*D + lg*8);
            acc = MFMA16(aV[h], bV, acc);
        }
        const int m = mb + lr;
        if (m < N) {
            #pragma unroll
            for (int j = 0; j < 4; ++j) {
                const int n = n0 + lg*4 + j;
                Mask[(size_t)n*N + m] = (acc[j]*0.125f > 0.75f) ? (unsigned char)1 : (unsigned char)0;
            }
        }
    }
}

// ================= K4: fused attention — swapped-operand MFMA, register softmax, 1 barrier =================
__global__ __launch_bounds__(256) void attn_kernel(
    const _Float16* __restrict__ Qch, const _Float16* __restrict__ Kch,
    const _Float16* __restrict__ Qrh, const _Float16* __restrict__ Krh,
    const _Float16* __restrict__ Vth, const float* __restrict__ coord,
    const float* __restrict__ clsScore, const float* __restrict__ fgScore,
    const float* __restrict__ STi,
    float* __restrict__ SIM, _Float16* __restrict__ XPH)
{
    __shared__ _Float16 pvred[4][H][2][16][17];

    const int t = threadIdx.x;
    const int w = t >> 6, l = t & 63;
    const int lr = l & 15, lg = l >> 4;
    const int mc = blockIdx.x;            // 0..7
    const int m0 = mc * 256;
    const int n0 = blockIdx.y * 16;
    const int n  = n0 + lr;               // this lane's q-row (swapped layout)
    const int bs = (n / 10) * 10;
    const int cb = w * 64;

    int mb[4]; bool ok[4];
    #pragma unroll
    for (int s = 0; s < 4; ++s) { mb[s] = m0 + cb + s*16; ok[s] = mb[s] < N; }

    float simacc[4][4];
    #pragma unroll
    for (int s = 0; s < 4; ++s)
        #pragma unroll
        for (int j = 0; j < 4; ++j) simacc[s][j] = 0.f;

    // coord prefetch for head 0 (per-lane float4: 4 consecutive m)
    f32x4 co[4];
    #pragma unroll
    for (int s = 0; s < 4; ++s)
        co[s] = ok[s] ? *(const f32x4*)(coord + (size_t)n*N + mb[s] + lg*4)
                      : (f32x4){0.f,0.f,0.f,0.f};

    for (int h = 0; h < H; ++h) {
        // prefetch next head's coord while this head computes
        f32x4 coN[4];
        if (h < H-1) {
            #pragma unroll
            for (int s = 0; s < 4; ++s)
                coN[s] = ok[s] ? *(const f32x4*)(coord + ((size_t)(h+1)*N + n)*N + mb[s] + lg*4)
                               : (f32x4){0.f,0.f,0.f,0.f};
        }
        const float iC = STi[((size_t)0*H + h)*NP + n];
        const float iR = STi[((size_t)1*H + h)*NP + n];
        const half8 aQc = *(const half8*)(Qch + ((size_t)h*NP + n)*D + lg*8);
        const half8 aQr = *(const half8*)(Qrh + ((size_t)h*NP + n)*D + lg*8);

        f32x4 pv0 = {0.f,0.f,0.f,0.f}, pv1 = {0.f,0.f,0.f,0.f};
        #pragma unroll
        for (int s = 0; s < 4; ++s) {
            if (!ok[s]) continue;   // wave-uniform
            const half8 bKc = *(const half8*)(Kch + ((size_t)h*NP + mb[s] + lr)*D + lg*8);
            const half8 bKr = *(const half8*)(Krh + ((size_t)h*NP + mb[s] + lr)*D + lg*8);
            f32x4 z4 = {0.f,0.f,0.f,0.f};
            // swapped operands: lane holds S[q = n0+lr][m = mb + lg*4 + j]
            const f32x4 cc = MFMA16(bKc, aQc, z4);
            const f32x4 cr = MFMA16(bKr, aQr, z4);
            const f32x4 sc4 = *(const f32x4*)(clsScore + mb[s] + lg*4);
            const f32x4 sf4 = *(const f32x4*)(fgScore + mb[s] + lg*4);
            half4 af;
            #pragma unroll
            for (int j = 0; j < 4; ++j) {
                const int m = mb[s] + lg*4 + j;
                float a = (__expf(fmaf(cc[j], SCL*sc4[j], -FM)) * iC
                         + __expf(fmaf(cr[j], SCL*sf4[j], -FM)) * iR) * 0.5f * co[s][j];
                if (m >= bs && m < bs+9 && m != n) a = 0.f;
                simacc[s][j] += a;
                af[j] = (_Float16)a;
            }
            // PV: att fragment is already in A-layout for 16x16x16 (k = 16-wide subtile)
            const half4 bV0 = *(const half4*)(Vth + ((size_t)h*D + lr)*NP + mb[s] + lg*4);
            const half4 bV1 = *(const half4*)(Vth + ((size_t)h*D + 16 + lr)*NP + mb[s] + lg*4);
            pv0 = MFMA16K(af, bV0, pv0);
            pv1 = MFMA16K(af, bV1, pv1);
        }
        // pv layout: pv[db][j] = X[q = n0 + lg*4 + j][d = db*16 + lr] — own-wave LDS write, no barrier
        #pragma unroll
        for (int j = 0; j < 4; ++j) {
            pvred[w][h][0][lg*4 + j][lr] = (_Float16)pv0[j];
            pvred[w][h][1][lg*4 + j][lr] = (_Float16)pv1[j];
        }
        #pragma unroll
        for (int s = 0; s < 4; ++s) co[s] = coN[s];
    }

    __syncthreads();   // the ONLY barrier

    // cross-wave reduce: 8h x 2db x 16r x 16d = 4096 elems
    for (int e = t; e < 4096; e += 256) {
        const int hh = e >> 9, db = (e >> 8) & 1, r = (e >> 4) & 15, d0 = e & 15;
        const float sum = (float)pvred[0][hh][db][r][d0] + (float)pvred[1][hh][db][r][d0]
                        + (float)pvred[2][hh][db][r][d0] + (float)pvred[3][hh][db][r][d0];
        XPH[(((size_t)mc*H + hh)*N + n0 + r)*D + db*16 + d0] = (_Float16)sum;
    }

    // SIM stores: float4 per subtile
    #pragma unroll
    for (int s = 0; s < 4; ++s) {
        if (!ok[s]) continue;
        f32x4 v;
        #pragma unroll
        for (int j = 0; j < 4; ++j) v[j] = simacc[s][j] * 0.125f;
        *(f32x4*)(SIM + (size_t)n*N + mb[s] + lg*4) = v;
    }
}

// ================= K5: reduce XP partials -> x =================
__global__ __launch_bounds__(256) void reduce_kernel(
    const _Float16* __restrict__ XPH, float* __restrict__ out)
{
    const int n = blockIdx.x, t = threadIdx.x;
    const int h = t >> 5, d = t & 31;
    float acc = 0.f;
    #pragma unroll
    for (int mcI = 0; mcI < 8; ++mcI)
        acc += (float)XPH[(((size_t)mcI*H + h)*N + n)*D + d];
    out[(size_t)n*512 + t] = acc;
}

// ================= K6: row softmax of SIM + masked renorm (float4) =================
__global__ __launch_bounds__(256) void simfinal_kernel(
    const float* __restrict__ SIM, const unsigned char* __restrict__ Mask,
    float* __restrict__ out)
{
    __shared__ float4 buf[500];
    __shared__ float redA[4], redB[4];
    const int n = blockIdx.x, t = threadIdx.x;
    const float4* row4 = (const float4*)(SIM + (size_t)n*N);
    const uchar4* mrow4 = (const uchar4*)(Mask + (size_t)n*N);
    float mx = -1e30f;
    for (int i = t; i < 500; i += 256) {
        const float4 v = row4[i];
        buf[i] = v;
        mx = fmaxf(mx, fmaxf(fmaxf(v.x, v.y), fmaxf(v.z, v.w)));
    }
    #pragma unroll
    for (int off = 1; off < 64; off <<= 1) mx = fmaxf(mx, __shfl_xor(mx, off));
    const int wv = t >> 6;
    if ((t & 63) == 0) redA[wv] = mx;
    __syncthreads();
    const float M = fmaxf(fmaxf(redA[0], redA[1]), fmaxf(redA[2], redA[3]));
    float sA = 0.f, sM = 0.f;
    for (int i = t; i < 500; i += 256) {
        float4 v = buf[i];
        const uchar4 mk = mrow4[i];
        v.x = __expf(v.x - M); v.y = __expf(v.y - M);
        v.z = __expf(v.z - M); v.w = __expf(v.w - M);
        buf[i] = v;
        sA += v.x + v.y + v.z + v.w;
        sM += (mk.x ? v.x : 0.f) + (mk.y ? v.y : 0.f) + (mk.z ? v.z : 0.f) + (mk.w ? v.w : 0.f);
    }
    #pragma unroll
    for (int off = 1; off < 64; off <<= 1) { sA += __shfl_xor(sA, off); sM += __shfl_xor(sM, off); }
    __syncthreads();
    if ((t & 63) == 0) { redA[wv] = sA; redB[wv] = sM; }
    __syncthreads();
    const float SA = redA[0] + redA[1] + redA[2] + redA[3];
    const float SMK = redB[0] + redB[1] + redB[2] + redB[3];
    const float inv = 1.f / (SMK + 1e-8f * SA);
    float4* orow = (float4*)(out + 1024000 + (size_t)n*N);
    for (int i = t; i < 500; i += 256) {
        const float4 v = buf[i];
        const uchar4 mk = mrow4[i];
        orow[i] = make_float4(mk.x ? v.x * inv : 0.f, mk.y ? v.y * inv : 0.f,
                              mk.z ? v.z * inv : 0.f, mk.w ? v.w * inv : 0.f);
    }
}

extern "C" void kernel_launch(void* const* d_in, const int* in_sizes, int n_in,
                              void* d_out, int out_size, void* d_ws, size_t ws_size,
                              hipStream_t stream) {
    const float* x_cls     = (const float*)d_in[0];
    const float* x_reg     = (const float*)d_in[1];
    const float* cls_score = (const float*)d_in[2];
    const float* fg_score  = (const float*)d_in[3];
    const float* coord     = (const float*)d_in[4];
    const float* Wc        = (const float*)d_in[5];
    const float* Wr        = (const float*)d_in[6];

    char* base = (char*)d_ws;
    float* STi      = (float*)base;
    float* SIM      = (float*)(base + 131072);
    _Float16* XPH   = (_Float16*)(base + 16131072);
    _Float16* Qch   = (_Float16*)(base + 24323072);
    _Float16* Kch   = Qch + 524288;
    _Float16* Qrh   = Qch + 2*524288;
    _Float16* Krh   = Qch + 3*524288;
    _Float16* Vnh   = Qch + 4*524288;
    _Float16* Vth   = Qch + 5*524288;
    _Float16* Wch   = (_Float16*)(base + 30614528);
    _Float16* Wrh   = (_Float16*)(base + 31007744);
    unsigned char* Mask = (unsigned char*)(base + 31400960);
    float* out = (float*)d_out;

    hipMemsetAsync(Qch, 0, 6*1048576, stream);   // zero f16 tensors (covers pad rows/cols)
    wconv_kernel<<<768, 256, 0, stream>>>(Wc, Wr, Wch, Wrh);
    qkv_kernel<<<dim3(125, 5), 256, 0, stream>>>(x_cls, x_reg, Wch, Wrh,
                                                 Qch, Kch, Qrh, Krh, Vnh, Vth, out);
    stats_kernel<<<dim3(32, 8, 2), 512, 0, stream>>>(Qch, Kch, Qrh, Krh, cls_score, fg_score, STi);
    vvmask_kernel<<<dim3(8, 125), 256, 0, stream>>>(Vnh, Mask);
    attn_kernel<<<dim3(8, 125), 256, 0, stream>>>(Qch, Kch, Qrh, Krh, Vth, coord,
                                                  cls_score, fg_score, STi, SIM, XPH);
    reduce_kernel<<<2000, 256, 0, stream>>>(XPH, out);
    simfinal_kernel<<<2000, 256, 0, stream>>>(SIM, Mask, out);
}

// Round 6
// 142.393 us; speedup vs baseline: 1.1611x; 1.1611x over previous
//
#include <hip/hip_runtime.h>
#include <math.h>

typedef _Float16 half8 __attribute__((ext_vector_type(8)));
typedef _Float16 half4 __attribute__((ext_vector_type(4)));
typedef float f32x4 __attribute__((ext_vector_type(4)));

constexpr int N = 2000;
constexpr int NP = 2048;   // padded row count for f16 tensors
constexpr int H = 8;
constexpr int D = 32;
constexpr float SCL = 25.0f;
constexpr float FM = 25.0f;  // fixed softmax max (scores bounded by 25)

#define MFMA16(a,b,c)  __builtin_amdgcn_mfma_f32_16x16x32_f16((a),(b),(c),0,0,0)
#define MFMA16K(a,b,c) __builtin_amdgcn_mfma_f32_16x16x16f16((a),(b),(c),0,0,0)

// ---- ws layout (byte offsets) ----
// STi  f32 [2z][8h][2048]        @ 0          (131072 B)   stores 1/S
// SIM  f32 [2000][2000]          @ 131072     (16000000 B)
// XPH  f16 [16mc][8h][2000][32]  @ 16131072   (16384000 B)
// F16  Qch,Kch,Qrh,Krh,Vnh [8][2048][32]; Vth [8][32][2048] @ 32515072 (6x1048576 B)
// Wch  f16 [768][256]            @ 38806528   (393216 B)
// Wrh  f16 [768][256]            @ 39199744   (393216 B)
// Mask u8  [2000][2000]          @ 39592960   (4000000 B)   total ~43.6 MB

// ================= K0: convert W to f16 =================
__global__ __launch_bounds__(256) void wconv_kernel(
    const float* __restrict__ Wc, const float* __restrict__ Wr,
    _Float16* __restrict__ Wch, _Float16* __restrict__ Wrh)
{
    const int i = blockIdx.x * 256 + threadIdx.x;  // grid 768 -> 196608 exactly
    Wch[i] = (_Float16)Wc[i];
    Wrh[i] = (_Float16)Wr[i];
}

// ================= K1: QKV projection via MFMA + L2 norm =================
__global__ __launch_bounds__(256) void qkv_kernel(
    const float* __restrict__ xc, const float* __restrict__ xr,
    const _Float16* __restrict__ Wch, const _Float16* __restrict__ Wrh,
    _Float16* __restrict__ Qch, _Float16* __restrict__ Kch,
    _Float16* __restrict__ Qrh, _Float16* __restrict__ Krh,
    _Float16* __restrict__ Vnh, _Float16* __restrict__ Vth,
    float* __restrict__ out)
{
    constexpr int XS = 264;  // xs row stride (halfs), +8 pad
    __shared__ _Float16 xs[16 * XS];
    const int t = threadIdx.x;
    const int n0 = blockIdx.x * 16;
    const int by = blockIdx.y;             // 0..4: (cls q,k,v), (reg q,k)
    const int which = (by < 3) ? by : (by - 3);
    const bool isCls = by < 3;
    const float* x = isCls ? xc : xr;
    const _Float16* Wh = isCls ? Wch : Wrh;

    #pragma unroll
    for (int it = 0; it < 4; ++it) {
        const int f = t + it * 256;        // float4 index over 16x64
        const int row = f >> 6, c4 = f & 63;
        const float4 v = *(const float4*)(x + (size_t)(n0 + row) * 256 + c4 * 4);
        half4 hv; hv[0]=(_Float16)v.x; hv[1]=(_Float16)v.y; hv[2]=(_Float16)v.z; hv[3]=(_Float16)v.w;
        *(half4*)&xs[row * XS + c4 * 4] = hv;
    }
    __syncthreads();

    const int w = t >> 6, l = t & 63;
    const int lr = l & 15, lg = l >> 4;
    const int obase = which * 256 + w * 64;
    f32x4 acc[4] = {{0,0,0,0},{0,0,0,0},{0,0,0,0},{0,0,0,0}};
    for (int k0 = 0; k0 < 256; k0 += 32) {
        const half8 aX = *(const half8*)&xs[lr * XS + k0 + lg * 8];
        #pragma unroll
        for (int s = 0; s < 4; ++s) {
            const half8 bW = *(const half8*)(Wh + (size_t)(obase + s * 16 + lr) * 256 + k0 + lg * 8);
            acc[s] = MFMA16(aX, bW, acc[s]);
        }
    }
    #pragma unroll
    for (int p = 0; p < 2; ++p) {
        const int h = 2 * w + p;
        float ss[4];
        #pragma unroll
        for (int j = 0; j < 4; ++j) {
            float v = acc[2*p][j]*acc[2*p][j] + acc[2*p+1][j]*acc[2*p+1][j];
            #pragma unroll
            for (int off = 1; off < 16; off <<= 1) v += __shfl_xor(v, off);
            ss[j] = sqrtf(v) + 1e-8f;
        }
        if (which < 2) {
            _Float16* Qd = isCls ? (which == 0 ? Qch : Kch) : (which == 0 ? Qrh : Krh);
            #pragma unroll
            for (int sh = 0; sh < 2; ++sh)
                #pragma unroll
                for (int j = 0; j < 4; ++j)
                    Qd[((size_t)h*NP + n0 + lg*4 + j)*D + sh*16 + lr] = (_Float16)(acc[2*p+sh][j] / ss[j]);
        } else {
            #pragma unroll
            for (int sh = 0; sh < 2; ++sh) {
                const int d = sh * 16 + lr;
                half4 tv;
                #pragma unroll
                for (int j = 0; j < 4; ++j) {
                    const float raw = acc[2*p+sh][j];
                    Vnh[((size_t)h*NP + n0 + lg*4 + j)*D + d] = (_Float16)(raw / ss[j]);
                    out[(size_t)(n0 + lg*4 + j)*512 + 256 + h*D + d] = raw;
                    tv[j] = (_Float16)raw;
                }
                *(half4*)(Vth + ((size_t)h*D + d)*NP + n0 + lg*4) = tv;
            }
        }
    }
}

// ================= K2: softmax denom (fixed max M=25) via MFMA, stores 1/S =================
__global__ __launch_bounds__(512) void stats_kernel(
    const _Float16* __restrict__ Qch, const _Float16* __restrict__ Kch,
    const _Float16* __restrict__ Qrh, const _Float16* __restrict__ Krh,
    const float* __restrict__ clsScore, const float* __restrict__ fgScore,
    float* __restrict__ STi)
{
    __shared__ float Ssh[4][2][16];
    const int t = threadIdx.x;
    const int w = t >> 6, l = t & 63;
    const int nsub = w >> 1, mhalf = w & 1;
    const int n0 = blockIdx.x * 64 + nsub * 16;
    const int h = blockIdx.y, z = blockIdx.z;
    const _Float16* Q = z ? Qrh : Qch;
    const _Float16* K = z ? Krh : Kch;
    const float* score = z ? fgScore : clsScore;
    const int lr = l & 15, lg = l >> 4;
    const half8 aQ = *(const half8*)(Q + ((size_t)h*NP + n0 + lr)*D + lg*8);
    float S[4] = {0.f, 0.f, 0.f, 0.f};
    const int msBeg = mhalf ? 63 : 0;
    const int msEnd = mhalf ? 125 : 63;
    for (int ms = msBeg; ms < msEnd; ++ms) {
        const int m = ms * 16 + lr;
        const half8 bK = *(const half8*)(K + ((size_t)h*NP + m)*D + lg*8);
        f32x4 z4 = {0.f, 0.f, 0.f, 0.f};
        const f32x4 c = MFMA16(aQ, bK, z4);
        const float sm = SCL * score[m];
        #pragma unroll
        for (int j = 0; j < 4; ++j) S[j] += __expf(fmaf(c[j], sm, -FM));
    }
    #pragma unroll
    for (int j = 0; j < 4; ++j) {
        #pragma unroll
        for (int off = 1; off < 16; off <<= 1) S[j] += __shfl_xor(S[j], off);
    }
    if (lr == 0) {
        #pragma unroll
        for (int j = 0; j < 4; ++j) Ssh[nsub][mhalf][lg*4 + j] = S[j];
    }
    __syncthreads();
    if (t < 64) {
        const int ns = t >> 4, rl = t & 15;
        STi[((size_t)z*H + h)*NP + blockIdx.x*64 + ns*16 + rl]
            = 1.f / (Ssh[ns][0][rl] + Ssh[ns][1][rl]);
    }
}

// ================= K3: mean-over-h of Vn.Vn^T -> u8 mask (MFMA) =================
__global__ __launch_bounds__(256) void vvmask_kernel(
    const _Float16* __restrict__ Vnh, unsigned char* __restrict__ Mask)
{
    const int t = threadIdx.x;
    const int w = t >> 6, l = t & 63;
    const int n0 = blockIdx.y * 16;
    const int m00 = blockIdx.x * 256 + w * 64;
    const int lr = l & 15, lg = l >> 4;
    half8 aV[8];
    #pragma unroll
    for (int h = 0; h < 8; ++h)
        aV[h] = *(const half8*)(Vnh + ((size_t)(h*NP + n0 + lr))*D + lg*8);
    for (int s = 0; s < 4; ++s) {
        const int mb = m00 + s*16;
        f32x4 acc = {0.f, 0.f, 0.f, 0.f};
        #pragma unroll
        for (int h = 0; h < 8; ++h) {
            const half8 bV = *(const half8*)(Vnh + ((size_t)(h*NP + mb + lr))*D + lg*8);
            acc = MFMA16(aV[h], bV, acc);
        }
        const int m = mb + lr;
        if (m < N) {
            #pragma unroll
            for (int j = 0; j < 4; ++j) {
                const int n = n0 + lg*4 + j;
                Mask[(size_t)n*N + m] = (acc[j]*0.125f > 0.75f) ? (unsigned char)1 : (unsigned char)0;
            }
        }
    }
}

// ================= K4: fused attention — swapped MFMA, register softmax, dbuf pvred, 1 barrier/head =================
__global__ __launch_bounds__(256) void attn_kernel(
    const _Float16* __restrict__ Qch, const _Float16* __restrict__ Kch,
    const _Float16* __restrict__ Qrh, const _Float16* __restrict__ Krh,
    const _Float16* __restrict__ Vth, const float* __restrict__ coord,
    const float* __restrict__ clsScore, const float* __restrict__ fgScore,
    const float* __restrict__ STi,
    float* __restrict__ SIM, _Float16* __restrict__ XPH)
{
    // pvred[buf][wave][db][d(=lr)][q + 2 pad]
    __shared__ _Float16 pvred[2][4][2][16][18];

    const int t = threadIdx.x;
    const int w = t >> 6, l = t & 63;
    const int lr = l & 15, lg = l >> 4;
    const int mc = blockIdx.x;            // 0..15
    const int m0 = mc * 128;
    const int n0 = blockIdx.y * 16;
    const int n  = n0 + lr;               // this lane's q-row (swapped layout)
    const int bs = (n / 10) * 10;
    const int cb = w * 32;

    int mb[2]; bool ok[2];
    #pragma unroll
    for (int s = 0; s < 2; ++s) { mb[s] = m0 + cb + s*16; ok[s] = mb[s] < N; }

    // hoisted m-side scores (head-invariant)
    f32x4 sc4[2], sf4[2];
    #pragma unroll
    for (int s = 0; s < 2; ++s) {
        sc4[s] = ok[s] ? SCL * *(const f32x4*)(clsScore + mb[s] + lg*4) : (f32x4){0,0,0,0};
        sf4[s] = ok[s] ? SCL * *(const f32x4*)(fgScore  + mb[s] + lg*4) : (f32x4){0,0,0,0};
    }
    float simacc[2][4] = {{0,0,0,0},{0,0,0,0}};

    for (int h = 0; h < H; ++h) {
        const float iC = STi[((size_t)0*H + h)*NP + n];
        const float iR = STi[((size_t)1*H + h)*NP + n];
        const half8 aQc = *(const half8*)(Qch + ((size_t)h*NP + n)*D + lg*8);
        const half8 aQr = *(const half8*)(Qrh + ((size_t)h*NP + n)*D + lg*8);

        // independent PV accumulators per subtile (chain length 1)
        f32x4 pvA[2][2] = {{{0,0,0,0},{0,0,0,0}},{{0,0,0,0},{0,0,0,0}}};
        #pragma unroll
        for (int s = 0; s < 2; ++s) {
            if (!ok[s]) continue;   // wave-uniform
            const half8 bKc = *(const half8*)(Kch + ((size_t)h*NP + mb[s] + lr)*D + lg*8);
            const half8 bKr = *(const half8*)(Krh + ((size_t)h*NP + mb[s] + lr)*D + lg*8);
            const f32x4 co = *(const f32x4*)(coord + ((size_t)h*N + n)*N + mb[s] + lg*4);
            f32x4 z4 = {0.f,0.f,0.f,0.f};
            // swapped operands: lane holds S[q = n0+lr][m = mb[s] + lg*4 + j]
            const f32x4 cc = MFMA16(bKc, aQc, z4);
            const f32x4 cr = MFMA16(bKr, aQr, z4);
            half4 af;
            #pragma unroll
            for (int j = 0; j < 4; ++j) {
                const int m = mb[s] + lg*4 + j;
                float a = (__expf(fmaf(cc[j], sc4[s][j], -FM)) * iC
                         + __expf(fmaf(cr[j], sf4[s][j], -FM)) * iR) * 0.5f * co[j];
                if (m >= bs && m < bs+9 && m != n) a = 0.f;
                simacc[s][j] += a;
                af[j] = (_Float16)a;
            }
            const half4 bV0 = *(const half4*)(Vth + ((size_t)h*D + lr)*NP + mb[s] + lg*4);
            const half4 bV1 = *(const half4*)(Vth + ((size_t)h*D + 16 + lr)*NP + mb[s] + lg*4);
            pvA[s][0] = MFMA16K(af, bV0, pvA[s][0]);
            pvA[s][1] = MFMA16K(af, bV1, pvA[s][1]);
        }
        const f32x4 pv0 = pvA[0][0] + pvA[1][0];
        const f32x4 pv1 = pvA[0][1] + pvA[1][1];

        // pv layout: pv[db][j] = X[q = n0+lg*4+j][d = db*16+lr] -> store [d][q] contiguous in q
        const int buf = h & 1;
        half4 h0, h1;
        #pragma unroll
        for (int j = 0; j < 4; ++j) { h0[j] = (_Float16)pv0[j]; h1[j] = (_Float16)pv1[j]; }
        *(half4*)&pvred[buf][w][0][lr][lg*4] = h0;
        *(half4*)&pvred[buf][w][1][lr][lg*4] = h1;
        __syncthreads();
        // cross-wave reduce: 512 elems, e = q*32 + db*16 + d  -> coalesced XPH
        const size_t xbase = ((size_t)(mc*H + h)*N + n0)*D;
        #pragma unroll
        for (int e = t; e < 512; e += 256) {
            const int d = e & 15, db = (e >> 4) & 1, q = e >> 5;
            const float sum = (float)pvred[buf][0][db][d][q] + (float)pvred[buf][1][db][d][q]
                            + (float)pvred[buf][2][db][d][q] + (float)pvred[buf][3][db][d][q];
            XPH[xbase + e] = (_Float16)sum;
        }
        // no second barrier: next head writes the other pvred buffer
    }

    // SIM stores: float4 per subtile (head-summed in registers)
    #pragma unroll
    for (int s = 0; s < 2; ++s) {
        if (!ok[s]) continue;
        f32x4 v;
        #pragma unroll
        for (int j = 0; j < 4; ++j) v[j] = simacc[s][j] * 0.125f;
        *(f32x4*)(SIM + (size_t)n*N + mb[s] + lg*4) = v;
    }
}

// ================= K5: reduce XP partials -> x =================
__global__ __launch_bounds__(256) void reduce_kernel(
    const _Float16* __restrict__ XPH, float* __restrict__ out)
{
    const int n = blockIdx.x, t = threadIdx.x;
    const int h = t >> 5, d = t & 31;
    float acc = 0.f;
    #pragma unroll
    for (int mcI = 0; mcI < 16; ++mcI)
        acc += (float)XPH[(((size_t)mcI*H + h)*N + n)*D + d];
    out[(size_t)n*512 + t] = acc;
}

// ================= K6: row softmax of SIM + masked renorm (float4) =================
__global__ __launch_bounds__(256) void simfinal_kernel(
    const float* __restrict__ SIM, const unsigned char* __restrict__ Mask,
    float* __restrict__ out)
{
    __shared__ float4 buf[500];
    __shared__ float redA[4], redB[4];
    const int n = blockIdx.x, t = threadIdx.x;
    const float4* row4 = (const float4*)(SIM + (size_t)n*N);
    const uchar4* mrow4 = (const uchar4*)(Mask + (size_t)n*N);
    float mx = -1e30f;
    for (int i = t; i < 500; i += 256) {
        const float4 v = row4[i];
        buf[i] = v;
        mx = fmaxf(mx, fmaxf(fmaxf(v.x, v.y), fmaxf(v.z, v.w)));
    }
    #pragma unroll
    for (int off = 1; off < 64; off <<= 1) mx = fmaxf(mx, __shfl_xor(mx, off));
    const int wv = t >> 6;
    if ((t & 63) == 0) redA[wv] = mx;
    __syncthreads();
    const float M = fmaxf(fmaxf(redA[0], redA[1]), fmaxf(redA[2], redA[3]));
    float sA = 0.f, sM = 0.f;
    for (int i = t; i < 500; i += 256) {
        float4 v = buf[i];
        const uchar4 mk = mrow4[i];
        v.x = __expf(v.x - M); v.y = __expf(v.y - M);
        v.z = __expf(v.z - M); v.w = __expf(v.w - M);
        buf[i] = v;
        sA += v.x + v.y + v.z + v.w;
        sM += (mk.x ? v.x : 0.f) + (mk.y ? v.y : 0.f) + (mk.z ? v.z : 0.f) + (mk.w ? v.w : 0.f);
    }
    #pragma unroll
    for (int off = 1; off < 64; off <<= 1) { sA += __shfl_xor(sA, off); sM += __shfl_xor(sM, off); }
    __syncthreads();
    if ((t & 63) == 0) { redA[wv] = sA; redB[wv] = sM; }
    __syncthreads();
    const float SA = redA[0] + redA[1] + redA[2] + redA[3];
    const float SMK = redB[0] + redB[1] + redB[2] + redB[3];
    const float inv = 1.f / (SMK + 1e-8f * SA);
    float4* orow = (float4*)(out + 1024000 + (size_t)n*N);
    for (int i = t; i < 500; i += 256) {
        const float4 v = buf[i];
        const uchar4 mk = mrow4[i];
        orow[i] = make_float4(mk.x ? v.x * inv : 0.f, mk.y ? v.y * inv : 0.f,
                              mk.z ? v.z * inv : 0.f, mk.w ? v.w * inv : 0.f);
    }
}

extern "C" void kernel_launch(void* const* d_in, const int* in_sizes, int n_in,
                              void* d_out, int out_size, void* d_ws, size_t ws_size,
                              hipStream_t stream) {
    const float* x_cls     = (const float*)d_in[0];
    const float* x_reg     = (const float*)d_in[1];
    const float* cls_score = (const float*)d_in[2];
    const float* fg_score  = (const float*)d_in[3];
    const float* coord     = (const float*)d_in[4];
    const float* Wc        = (const float*)d_in[5];
    const float* Wr        = (const float*)d_in[6];

    char* base = (char*)d_ws;
    float* STi      = (float*)base;
    float* SIM      = (float*)(base + 131072);
    _Float16* XPH   = (_Float16*)(base + 16131072);
    _Float16* Qch   = (_Float16*)(base + 32515072);
    _Float16* Kch   = Qch + 524288;
    _Float16* Qrh   = Qch + 2*524288;
    _Float16* Krh   = Qch + 3*524288;
    _Float16* Vnh   = Qch + 4*524288;
    _Float16* Vth   = Qch + 5*524288;
    _Float16* Wch   = (_Float16*)(base + 38806528);
    _Float16* Wrh   = (_Float16*)(base + 39199744);
    unsigned char* Mask = (unsigned char*)(base + 39592960);
    float* out = (float*)d_out;

    wconv_kernel<<<768, 256, 0, stream>>>(Wc, Wr, Wch, Wrh);
    qkv_kernel<<<dim3(125, 5), 256, 0, stream>>>(x_cls, x_reg, Wch, Wrh,
                                                 Qch, Kch, Qrh, Krh, Vnh, Vth, out);
    stats_kernel<<<dim3(32, 8, 2), 512, 0, stream>>>(Qch, Kch, Qrh, Krh, cls_score, fg_score, STi);
    vvmask_kernel<<<dim3(8, 125), 256, 0, stream>>>(Vnh, Mask);
    attn_kernel<<<dim3(16, 125), 256, 0, stream>>>(Qch, Kch, Qrh, Krh, Vth, coord,
                                                   cls_score, fg_score, STi, SIM, XPH);
    reduce_kernel<<<2000, 256, 0, stream>>>(XPH, out);
    simfinal_kernel<<<2000, 256, 0, stream>>>(SIM, Mask, out);
}

// Round 7
// 142.162 us; speedup vs baseline: 1.1630x; 1.0016x over previous
//
#include <hip/hip_runtime.h>
#include <math.h>

typedef _Float16 half8 __attribute__((ext_vector_type(8)));
typedef _Float16 half4 __attribute__((ext_vector_type(4)));
typedef _Float16 half2v __attribute__((ext_vector_type(2)));
typedef float f32x4 __attribute__((ext_vector_type(4)));

constexpr int N = 2000;
constexpr int NP = 2048;   // padded row count for f16 tensors
constexpr int H = 8;
constexpr int D = 32;
constexpr float SCL = 25.0f;
constexpr float L2E = 1.4426950408889634f;
constexpr float FM2 = 25.0f * L2E;   // fixed softmax max (log2 domain)

#define MFMA16(a,b,c)  __builtin_amdgcn_mfma_f32_16x16x32_f16((a),(b),(c),0,0,0)
#define MFMA16K(a,b,c) __builtin_amdgcn_mfma_f32_16x16x16f16((a),(b),(c),0,0,0)

__device__ __forceinline__ float fexp2(float x) { return __builtin_amdgcn_exp2f(x); }

// ---- ws layout (byte offsets) ----
// STi  f32 [2z][8h][2048]        @ 0          (131072 B)   stores 1/S
// SIMH f16 [2000][2000]          @ 131072     (8000000 B)
// XPH  f16 [16mc][8h][2000][32]  @ 8131072    (16384000 B)
// F16  Qch,Kch,Qrh,Krh,Vnh [8][2048][32]; Vth [8][32][2048] @ 24515072 (6x1048576 B)
// Wch  f16 [768][256]            @ 30806528   (393216 B)
// Wrh  f16 [768][256]            @ 31199744   (393216 B)
// Mask u8  [2000][2000]          @ 31592960   (4000000 B)   total ~35.6 MB

// ================= K0: convert W to f16 =================
__global__ __launch_bounds__(256) void wconv_kernel(
    const float* __restrict__ Wc, const float* __restrict__ Wr,
    _Float16* __restrict__ Wch, _Float16* __restrict__ Wrh)
{
    const int i = blockIdx.x * 256 + threadIdx.x;  // grid 768 -> 196608 exactly
    Wch[i] = (_Float16)Wc[i];
    Wrh[i] = (_Float16)Wr[i];
}

// ================= K1: QKV projection via MFMA + L2 norm =================
__global__ __launch_bounds__(256) void qkv_kernel(
    const float* __restrict__ xc, const float* __restrict__ xr,
    const _Float16* __restrict__ Wch, const _Float16* __restrict__ Wrh,
    _Float16* __restrict__ Qch, _Float16* __restrict__ Kch,
    _Float16* __restrict__ Qrh, _Float16* __restrict__ Krh,
    _Float16* __restrict__ Vnh, _Float16* __restrict__ Vth,
    float* __restrict__ out)
{
    constexpr int XS = 264;  // xs row stride (halfs), +8 pad
    __shared__ _Float16 xs[16 * XS];
    const int t = threadIdx.x;
    const int n0 = blockIdx.x * 16;
    const int by = blockIdx.y;             // 0..4: (cls q,k,v), (reg q,k)
    const int which = (by < 3) ? by : (by - 3);
    const bool isCls = by < 3;
    const float* x = isCls ? xc : xr;
    const _Float16* Wh = isCls ? Wch : Wrh;

    #pragma unroll
    for (int it = 0; it < 4; ++it) {
        const int f = t + it * 256;        // float4 index over 16x64
        const int row = f >> 6, c4 = f & 63;
        const float4 v = *(const float4*)(x + (size_t)(n0 + row) * 256 + c4 * 4);
        half4 hv; hv[0]=(_Float16)v.x; hv[1]=(_Float16)v.y; hv[2]=(_Float16)v.z; hv[3]=(_Float16)v.w;
        *(half4*)&xs[row * XS + c4 * 4] = hv;
    }
    __syncthreads();

    const int w = t >> 6, l = t & 63;
    const int lr = l & 15, lg = l >> 4;
    const int obase = which * 256 + w * 64;
    f32x4 acc[4] = {{0,0,0,0},{0,0,0,0},{0,0,0,0},{0,0,0,0}};
    for (int k0 = 0; k0 < 256; k0 += 32) {
        const half8 aX = *(const half8*)&xs[lr * XS + k0 + lg * 8];
        #pragma unroll
        for (int s = 0; s < 4; ++s) {
            const half8 bW = *(const half8*)(Wh + (size_t)(obase + s * 16 + lr) * 256 + k0 + lg * 8);
            acc[s] = MFMA16(aX, bW, acc[s]);
        }
    }
    #pragma unroll
    for (int p = 0; p < 2; ++p) {
        const int h = 2 * w + p;
        float ss[4];
        #pragma unroll
        for (int j = 0; j < 4; ++j) {
            float v = acc[2*p][j]*acc[2*p][j] + acc[2*p+1][j]*acc[2*p+1][j];
            #pragma unroll
            for (int off = 1; off < 16; off <<= 1) v += __shfl_xor(v, off);
            ss[j] = sqrtf(v) + 1e-8f;
        }
        if (which < 2) {
            _Float16* Qd = isCls ? (which == 0 ? Qch : Kch) : (which == 0 ? Qrh : Krh);
            #pragma unroll
            for (int sh = 0; sh < 2; ++sh)
                #pragma unroll
                for (int j = 0; j < 4; ++j)
                    Qd[((size_t)h*NP + n0 + lg*4 + j)*D + sh*16 + lr] = (_Float16)(acc[2*p+sh][j] / ss[j]);
        } else {
            #pragma unroll
            for (int sh = 0; sh < 2; ++sh) {
                const int d = sh * 16 + lr;
                half4 tv;
                #pragma unroll
                for (int j = 0; j < 4; ++j) {
                    const float raw = acc[2*p+sh][j];
                    Vnh[((size_t)h*NP + n0 + lg*4 + j)*D + d] = (_Float16)(raw / ss[j]);
                    out[(size_t)(n0 + lg*4 + j)*512 + 256 + h*D + d] = raw;
                    tv[j] = (_Float16)raw;
                }
                *(half4*)(Vth + ((size_t)h*D + d)*NP + n0 + lg*4) = tv;
            }
        }
    }
}

// ================= K2: softmax denom (fixed max, exp2 domain) via MFMA, 2-deep pipeline =================
__global__ __launch_bounds__(512) void stats_kernel(
    const _Float16* __restrict__ Qch, const _Float16* __restrict__ Kch,
    const _Float16* __restrict__ Qrh, const _Float16* __restrict__ Krh,
    const float* __restrict__ clsScore, const float* __restrict__ fgScore,
    float* __restrict__ STi)
{
    __shared__ float Ssh[4][2][16];
    const int t = threadIdx.x;
    const int w = t >> 6, l = t & 63;
    const int nsub = w >> 1, mhalf = w & 1;
    const int n0 = blockIdx.x * 64 + nsub * 16;
    const int h = blockIdx.y, z = blockIdx.z;
    const _Float16* Q = z ? Qrh : Qch;
    const _Float16* K = z ? Krh : Kch;
    const float* score = z ? fgScore : clsScore;
    const int lr = l & 15, lg = l >> 4;
    const half8 aQ = *(const half8*)(Q + ((size_t)h*NP + n0 + lr)*D + lg*8);
    float S[4] = {0.f, 0.f, 0.f, 0.f};
    const int msBeg = mhalf ? 63 : 0;
    const int msEnd = mhalf ? 125 : 63;
    half8 bK = *(const half8*)(K + ((size_t)h*NP + msBeg*16 + lr)*D + lg*8);
    float sc = score[msBeg*16 + lr];
    for (int ms = msBeg; ms < msEnd; ++ms) {
        const half8 cur = bK;
        const float scc = sc;
        if (ms + 1 < msEnd) {
            bK = *(const half8*)(K + ((size_t)h*NP + (ms+1)*16 + lr)*D + lg*8);
            sc = score[(ms+1)*16 + lr];
        }
        f32x4 z4 = {0.f, 0.f, 0.f, 0.f};
        const f32x4 c = MFMA16(aQ, cur, z4);
        const float sm2 = scc * (SCL * L2E);
        #pragma unroll
        for (int j = 0; j < 4; ++j) S[j] += fexp2(fmaf(c[j], sm2, -FM2));
    }
    #pragma unroll
    for (int j = 0; j < 4; ++j) {
        #pragma unroll
        for (int off = 1; off < 16; off <<= 1) S[j] += __shfl_xor(S[j], off);
    }
    if (lr == 0) {
        #pragma unroll
        for (int j = 0; j < 4; ++j) Ssh[nsub][mhalf][lg*4 + j] = S[j];
    }
    __syncthreads();
    if (t < 64) {
        const int ns = t >> 4, rl = t & 15;
        STi[((size_t)z*H + h)*NP + blockIdx.x*64 + ns*16 + rl]
            = 1.f / (Ssh[ns][0][rl] + Ssh[ns][1][rl]);
    }
}

// ================= K3: mean-over-h of Vn.Vn^T -> u8 mask (MFMA) =================
__global__ __launch_bounds__(256) void vvmask_kernel(
    const _Float16* __restrict__ Vnh, unsigned char* __restrict__ Mask)
{
    const int t = threadIdx.x;
    const int w = t >> 6, l = t & 63;
    const int n0 = blockIdx.y * 16;
    const int m00 = blockIdx.x * 256 + w * 64;
    const int lr = l & 15, lg = l >> 4;
    half8 aV[8];
    #pragma unroll
    for (int h = 0; h < 8; ++h)
        aV[h] = *(const half8*)(Vnh + ((size_t)(h*NP + n0 + lr))*D + lg*8);
    for (int s = 0; s < 4; ++s) {
        const int mb = m00 + s*16;
        f32x4 acc = {0.f, 0.f, 0.f, 0.f};
        #pragma unroll
        for (int h = 0; h < 8; ++h) {
            const half8 bV = *(const half8*)(Vnh + ((size_t)(h*NP + mb + lr))*D + lg*8);
            acc = MFMA16(aV[h], bV, acc);
        }
        const int m = mb + lr;
        if (m < N) {
            #pragma unroll
            for (int j = 0; j < 4; ++j) {
                const int n = n0 + lg*4 + j;
                Mask[(size_t)n*N + m] = (acc[j]*0.125f > 0.75f) ? (unsigned char)1 : (unsigned char)0;
            }
        }
    }
}

// ================= K4: fused attention — pipelined heads, LDS-only barrier =================
struct Stage {
    half8 aQc, aQr;
    half8 bKc[2], bKr[2];
    f32x4 co[2];
    float iC, iR;
};

__global__ __launch_bounds__(256) void attn_kernel(
    const _Float16* __restrict__ Qch, const _Float16* __restrict__ Kch,
    const _Float16* __restrict__ Qrh, const _Float16* __restrict__ Krh,
    const _Float16* __restrict__ Vth, const float* __restrict__ coord,
    const float* __restrict__ clsScore, const float* __restrict__ fgScore,
    const float* __restrict__ STi,
    _Float16* __restrict__ SIMH, _Float16* __restrict__ XPH)
{
    // pvred[buf][wave][db][d(=lr)][q + 2 pad]
    __shared__ _Float16 pvred[2][4][2][16][18];

    const int t = threadIdx.x;
    const int w = t >> 6, l = t & 63;
    const int lr = l & 15, lg = l >> 4;
    const int mc = blockIdx.x;            // 0..15
    const int m0 = mc * 128;
    const int n0 = blockIdx.y * 16;
    const int n  = n0 + lr;               // this lane's q-row (swapped layout)
    const int bs = (n / 10) * 10;
    const int cb = w * 32;

    int mb[2]; bool ok[2];
    #pragma unroll
    for (int s = 0; s < 2; ++s) { mb[s] = m0 + cb + s*16; ok[s] = mb[s] < N; }

    // hoisted m-side scores, pre-scaled into log2 domain (head-invariant)
    f32x4 sc4[2], sf4[2];
    #pragma unroll
    for (int s = 0; s < 2; ++s) {
        sc4[s] = ok[s] ? (SCL*L2E) * *(const f32x4*)(clsScore + mb[s] + lg*4) : (f32x4){0,0,0,0};
        sf4[s] = ok[s] ? (SCL*L2E) * *(const f32x4*)(fgScore  + mb[s] + lg*4) : (f32x4){0,0,0,0};
    }
    float simacc[2][4] = {{0,0,0,0},{0,0,0,0}};

    auto loadStage = [&](int h, Stage& st) {
        st.iC = STi[(size_t)h*NP + n];
        st.iR = STi[((size_t)(H + h))*NP + n];
        st.aQc = *(const half8*)(Qch + ((size_t)h*NP + n)*D + lg*8);
        st.aQr = *(const half8*)(Qrh + ((size_t)h*NP + n)*D + lg*8);
        #pragma unroll
        for (int s = 0; s < 2; ++s) {
            if (ok[s]) {
                st.bKc[s] = *(const half8*)(Kch + ((size_t)h*NP + mb[s] + lr)*D + lg*8);
                st.bKr[s] = *(const half8*)(Krh + ((size_t)h*NP + mb[s] + lr)*D + lg*8);
                st.co[s]  = *(const f32x4*)(coord + ((size_t)h*N + n)*N + mb[s] + lg*4);
            }
        }
    };

    auto computeHead = [&](int h, const Stage& st) {
        // V loads issued early; consumed ~after QK+exp -> latency hidden
        half4 bV0[2], bV1[2];
        #pragma unroll
        for (int s = 0; s < 2; ++s) if (ok[s]) {
            bV0[s] = *(const half4*)(Vth + ((size_t)(h*D + lr))*NP + mb[s] + lg*4);
            bV1[s] = *(const half4*)(Vth + ((size_t)(h*D + 16 + lr))*NP + mb[s] + lg*4);
        }
        f32x4 pvA[2][2] = {{{0,0,0,0},{0,0,0,0}},{{0,0,0,0},{0,0,0,0}}};
        #pragma unroll
        for (int s = 0; s < 2; ++s) {
            if (!ok[s]) continue;   // wave-uniform
            f32x4 z4 = {0.f,0.f,0.f,0.f};
            // swapped operands: lane holds S[q = n0+lr][m = mb[s] + lg*4 + j]
            const f32x4 cc = MFMA16(st.bKc[s], st.aQc, z4);
            const f32x4 cr = MFMA16(st.bKr[s], st.aQr, z4);
            half4 af;
            #pragma unroll
            for (int j = 0; j < 4; ++j) {
                const int m = mb[s] + lg*4 + j;
                float a = (fexp2(fmaf(cc[j], sc4[s][j], -FM2)) * st.iC
                         + fexp2(fmaf(cr[j], sf4[s][j], -FM2)) * st.iR) * 0.5f * st.co[s][j];
                if (m >= bs && m < bs+9 && m != n) a = 0.f;
                simacc[s][j] += a;
                af[j] = (_Float16)a;
            }
            pvA[s][0] = MFMA16K(af, bV0[s], pvA[s][0]);
            pvA[s][1] = MFMA16K(af, bV1[s], pvA[s][1]);
        }
        const f32x4 pv0 = pvA[0][0] + pvA[1][0];
        const f32x4 pv1 = pvA[0][1] + pvA[1][1];
        const int buf = h & 1;
        half4 h0, h1;
        #pragma unroll
        for (int j = 0; j < 4; ++j) { h0[j] = (_Float16)pv0[j]; h1[j] = (_Float16)pv1[j]; }
        *(half4*)&pvred[buf][w][0][lr][lg*4] = h0;
        *(half4*)&pvred[buf][w][1][lr][lg*4] = h1;
        // LDS-only barrier: prefetched global loads stay in flight (no vmcnt drain)
        asm volatile("s_waitcnt lgkmcnt(0)" ::: "memory");
        __builtin_amdgcn_s_barrier();
        // cross-wave reduce: thread handles elems e=2t, 2t+1 -> one 4B store
        const size_t xbase = ((size_t)(mc*H + h)*N + n0)*D;
        {
            const int e0 = 2*t;
            const int d = e0 & 15, db = (e0 >> 4) & 1, q = e0 >> 5;
            const float s0 = (float)pvred[buf][0][db][d][q]   + (float)pvred[buf][1][db][d][q]
                           + (float)pvred[buf][2][db][d][q]   + (float)pvred[buf][3][db][d][q];
            const float s1 = (float)pvred[buf][0][db][d+1][q] + (float)pvred[buf][1][db][d+1][q]
                           + (float)pvred[buf][2][db][d+1][q] + (float)pvred[buf][3][db][d+1][q];
            half2v o; o[0] = (_Float16)s0; o[1] = (_Float16)s1;
            *(half2v*)(XPH + xbase + e0) = o;
        }
        // no second barrier: next head writes the other pvred buffer
    };

    Stage A, B;
    loadStage(0, A);
    #pragma unroll
    for (int hp = 0; hp < H; hp += 2) {
        loadStage(hp + 1, B);
        computeHead(hp, A);
        if (hp + 2 < H) loadStage(hp + 2, A);
        computeHead(hp + 1, B);
    }

    // SIM stores: f16 half4 per subtile (head-summed in registers)
    #pragma unroll
    for (int s = 0; s < 2; ++s) {
        if (!ok[s]) continue;
        half4 v;
        #pragma unroll
        for (int j = 0; j < 4; ++j) v[j] = (_Float16)(simacc[s][j] * 0.125f);
        *(half4*)(SIMH + (size_t)n*N + mb[s] + lg*4) = v;
    }
}

// ================= K5: reduce XP partials -> x =================
__global__ __launch_bounds__(256) void reduce_kernel(
    const _Float16* __restrict__ XPH, float* __restrict__ out)
{
    const int n = blockIdx.x, t = threadIdx.x;
    const int h = t >> 5, d = t & 31;
    float acc = 0.f;
    #pragma unroll
    for (int mcI = 0; mcI < 16; ++mcI)
        acc += (float)XPH[(((size_t)mcI*H + h)*N + n)*D + d];
    out[(size_t)n*512 + t] = acc;
}

// ================= K6: row softmax of SIMH + masked renorm (register-resident) =================
__global__ __launch_bounds__(256) void simfinal_kernel(
    const _Float16* __restrict__ SIMH, const unsigned char* __restrict__ Mask,
    float* __restrict__ out)
{
    __shared__ float redA[4], redB[4];
    const int n = blockIdx.x, t = threadIdx.x;
    const _Float16* row = SIMH + (size_t)n * N;
    const unsigned char* mrow = Mask + (size_t)n * N;
    const bool act = t < 250;                 // 250 x 8 halfs = 2000
    float f[8];
    unsigned int mk0 = 0, mk1 = 0;
    float mx = -1e30f;
    if (act) {
        const half8 v8 = *(const half8*)(row + t*8);
        const uint2 mm = *(const uint2*)(mrow + t*8);
        mk0 = mm.x; mk1 = mm.y;
        #pragma unroll
        for (int k = 0; k < 8; ++k) { f[k] = (float)v8[k]; mx = fmaxf(mx, f[k]); }
    }
    #pragma unroll
    for (int off = 1; off < 64; off <<= 1) mx = fmaxf(mx, __shfl_xor(mx, off));
    const int wv = t >> 6;
    if ((t & 63) == 0) redA[wv] = mx;
    __syncthreads();
    const float M = fmaxf(fmaxf(redA[0], redA[1]), fmaxf(redA[2], redA[3]));
    float e[8];
    float sA = 0.f, sM = 0.f;
    if (act) {
        #pragma unroll
        for (int k = 0; k < 8; ++k) {
            e[k] = fexp2((f[k] - M) * L2E);
            sA += e[k];
            const unsigned int mkb = ((k < 4 ? mk0 : mk1) >> (8*(k & 3))) & 0xffu;
            if (mkb) sM += e[k]; else e[k] = 0.f;
        }
    }
    #pragma unroll
    for (int off = 1; off < 64; off <<= 1) { sA += __shfl_xor(sA, off); sM += __shfl_xor(sM, off); }
    __syncthreads();
    if ((t & 63) == 0) { redA[wv] = sA; redB[wv] = sM; }
    __syncthreads();
    const float SA = redA[0] + redA[1] + redA[2] + redA[3];
    const float SMK = redB[0] + redB[1] + redB[2] + redB[3];
    const float inv = 1.f / (SMK + 1e-8f * SA);
    if (act) {
        float* orow = out + 1024000 + (size_t)n*N + t*8;
        *(float4*)(orow)     = make_float4(e[0]*inv, e[1]*inv, e[2]*inv, e[3]*inv);
        *(float4*)(orow + 4) = make_float4(e[4]*inv, e[5]*inv, e[6]*inv, e[7]*inv);
    }
}

extern "C" void kernel_launch(void* const* d_in, const int* in_sizes, int n_in,
                              void* d_out, int out_size, void* d_ws, size_t ws_size,
                              hipStream_t stream) {
    const float* x_cls     = (const float*)d_in[0];
    const float* x_reg     = (const float*)d_in[1];
    const float* cls_score = (const float*)d_in[2];
    const float* fg_score  = (const float*)d_in[3];
    const float* coord     = (const float*)d_in[4];
    const float* Wc        = (const float*)d_in[5];
    const float* Wr        = (const float*)d_in[6];

    char* base = (char*)d_ws;
    float* STi      = (float*)base;
    _Float16* SIMH  = (_Float16*)(base + 131072);
    _Float16* XPH   = (_Float16*)(base + 8131072);
    _Float16* Qch   = (_Float16*)(base + 24515072);
    _Float16* Kch   = Qch + 524288;
    _Float16* Qrh   = Qch + 2*524288;
    _Float16* Krh   = Qch + 3*524288;
    _Float16* Vnh   = Qch + 4*524288;
    _Float16* Vth   = Qch + 5*524288;
    _Float16* Wch   = (_Float16*)(base + 30806528);
    _Float16* Wrh   = (_Float16*)(base + 31199744);
    unsigned char* Mask = (unsigned char*)(base + 31592960);
    float* out = (float*)d_out;

    wconv_kernel<<<768, 256, 0, stream>>>(Wc, Wr, Wch, Wrh);
    qkv_kernel<<<dim3(125, 5), 256, 0, stream>>>(x_cls, x_reg, Wch, Wrh,
                                                 Qch, Kch, Qrh, Krh, Vnh, Vth, out);
    stats_kernel<<<dim3(32, 8, 2), 512, 0, stream>>>(Qch, Kch, Qrh, Krh, cls_score, fg_score, STi);
    vvmask_kernel<<<dim3(8, 125), 256, 0, stream>>>(Vnh, Mask);
    attn_kernel<<<dim3(16, 125), 256, 0, stream>>>(Qch, Kch, Qrh, Krh, Vth, coord,
                                                   cls_score, fg_score, STi, SIMH, XPH);
    reduce_kernel<<<2000, 256, 0, stream>>>(XPH, out);
    simfinal_kernel<<<2000, 256, 0, stream>>>(SIMH, Mask, out);
}